// Round 7
// baseline (484.247 us; speedup 1.0000x reference)
//
#include <hip/hip_runtime.h>
#include <cstdint>
#include <cstddef>

#define B_   4096
#define T_   128
#define IN_  768
#define H_   256
#define BM_  128          // batch rows per workgroup
#define KC1  (IN_ / 32)   // 24 32k-chunks (transform granularity)
#define NS1  48           // layer-1 k16 steps
#define NS2  16           // layer-2 k16 steps

typedef __bf16 bf16_t;
typedef bf16_t bf16x8 __attribute__((ext_vector_type(8)));
typedef bf16_t bf16x4 __attribute__((ext_vector_type(4)));
typedef float  floatx16 __attribute__((ext_vector_type(16)));

#define MFMA32(a, b, c) __builtin_amdgcn_mfma_f32_32x32x16_bf16((a), (b), (c), 0, 0, 0)

__device__ __forceinline__ void lgkm0_barrier() {
    asm volatile("s_waitcnt lgkmcnt(0)" ::: "memory");
    __builtin_amdgcn_s_barrier();
    asm volatile("" ::: "memory");
}

// ---------------- transform kernel (verbatim from R6; proven) ----------------
__global__ __launch_bounds__(256)
void tile_all(const float* __restrict__ x, const float* __restrict__ W1,
              const float* __restrict__ W2, bf16_t* __restrict__ xt,
              bf16_t* __restrict__ w1t, bf16_t* __restrict__ w2t) {
    const int b   = blockIdx.x;
    const int tid = threadIdx.x;
    if (b < T_ * KC1 + T_ * 8) {
        const float* src; bf16_t* dst; int t, kc, K, KC;
        if (b < T_ * KC1) { t = b / KC1; kc = b - t * KC1; K = IN_; KC = KC1; src = W1; dst = w1t; }
        else { int bb = b - T_ * KC1; t = bb >> 3; kc = bb & 7; K = H_; KC = 8; src = W2; dst = w2t; }
        const int kq = tid >> 6, h4 = (tid & 63) * 4;
        const float* s = src + ((size_t)t * K + kc * 32 + kq * 8) * H_ + h4;
        float r[8][4];
#pragma unroll
        for (int e = 0; e < 8; ++e) {
            float4 v = *(const float4*)(s + (size_t)e * H_);
            r[e][0] = v.x; r[e][1] = v.y; r[e][2] = v.z; r[e][3] = v.w;
        }
        bf16_t* d = dst + (((size_t)(t * KC + kc) * 4 + kq) * H_ + h4) * 8;
#pragma unroll
        for (int c = 0; c < 4; ++c) {
            bf16x8 v;
#pragma unroll
            for (int e = 0; e < 8; ++e) v[e] = (bf16_t)r[e][c];
            *(bf16x8*)(d + c * 8) = v;
        }
    } else {
        const int bb = b - (T_ * KC1 + T_ * 8);
        const int mb = bb / KC1, kc = bb - mb * KC1;
        const int r = tid >> 3, c = tid & 7;
#pragma unroll
        for (int it = 0; it < 4; ++it) {
            const int m = it * 32 + r;
            float4 v = *(const float4*)(x + ((size_t)(mb * 128 + m)) * IN_ + kc * 32 + c * 4);
            bf16x4 o; o[0] = (bf16_t)v.x; o[1] = (bf16_t)v.y; o[2] = (bf16_t)v.z; o[3] = (bf16_t)v.w;
            *(bf16x4*)(xt + ((size_t)(mb * KC1 + kc) * 4 + (c >> 1)) * 1024 + m * 8 + (c & 1) * 4) = o;
        }
    }
}

// ---------------- fused MLP: reg staging, 2 WG/CU, x via LDS ring (no dup) ----------------
// h^T = W^T x^T. W ring-2 (8KB slots, wring) and x ring-2 (4KB slots aliased in
// hbuf's dead space) staged global->VGPR->ds_write with conflict-free split-half
// writes (lane stride 16B). Barriers = raw s_barrier + lgkmcnt(0); global loads
// (VGPR dest) float across them.
__global__ __launch_bounds__(256, 2)
void mtmlp_fused7(const bf16_t* __restrict__ xt, const bf16_t* __restrict__ w1t,
                  const float* __restrict__ b1, const bf16_t* __restrict__ w2t,
                  const float* __restrict__ b2, const float* __restrict__ W3,
                  const float* __restrict__ b3, float* __restrict__ out) {
    // Swizzle for L2 reuse (assumes consecutive ids round-robin over 8 XCDs):
    // XCD k pins mblks [4k,4k+4) (x tiles 768KB, L2-resident all kernel) and
    // walks tasks in order; 4 consecutive slots share one task's W via L2.
    const int L    = blockIdx.x;          // 0..4095
    const int xcd  = L & 7;
    const int s    = L >> 3;              // 0..511
    const int t    = s >> 2;              // 0..127
    const int mblk = xcd * 4 + (s & 3);   // 0..31
    const int m0   = mblk * BM_;

    const int tid  = threadIdx.x;
    const int lane = tid & 63;
    const int wid  = tid >> 6;            // 0..3
    const int wm   = wid & 1;             // h half (128)
    const int wn   = wid >> 1;            // m half (64)
    const int ln31 = lane & 31;
    const int hi   = lane >> 5;

    __shared__ __align__(16) bf16_t hbuf[BM_ * H_];   // 64 KB; x ring-2 aliased at [0,4096)
    __shared__ __align__(16) bf16_t wring[2 * 4096];  // 16 KB: ring-2 W slots; w3s alias
    float* w3s = (float*)wring;                       // slot0 alias (layer 3 only)

    floatx16 acc[2][2], acc2[2][2];
#pragma unroll
    for (int i = 0; i < 2; ++i)
#pragma unroll
        for (int j = 0; j < 2; ++j)
#pragma unroll
            for (int e = 0; e < 16; ++e) { acc[i][j][e] = 0.0f; acc2[i][j][e] = 0.0f; }

    const bf16_t* w1base = w1t + (size_t)t * NS1 * 4096;   // step image: 4096 elems
    const bf16_t* w2base = w2t + (size_t)t * NS2 * 4096;
    const bf16_t* xbase  = xt + (size_t)mblk * KC1 * 4096; // step image: 2048 elems

    bf16x8 wrA[2], wrB[2], xrA, xrB;

    auto loadW = [&](bf16x8* r, const bf16_t* base, int c) {   // 2x dwordx4, split halves
        const bf16_t* p = base + (size_t)c * 4096 + tid * 8;
        r[0] = *(const bf16x8*)(p);
        r[1] = *(const bf16x8*)(p + 2048);
    };
    auto writeW = [&](const bf16x8* r, int sl) {               // lane stride 16B: conflict-free
        bf16_t* p = wring + sl * 4096 + tid * 8;
        *(bf16x8*)(p)        = r[0];
        *(bf16x8*)(p + 2048) = r[1];
    };
    auto loadXg = [&](bf16x8& r, int c) {
        r = *(const bf16x8*)(xbase + (size_t)c * 2048 + tid * 8);
    };
    auto writeX = [&](const bf16x8& r, int sl) {
        *(bf16x8*)(hbuf + sl * 2048 + tid * 8) = r;
    };
    auto comp = [&](int wsl, int xsl) {    // W slot [kq2][h256][8], x slot [kq2][m128][8]
        const bf16_t* wb = wring + wsl * 4096;
        const bf16_t* xb = hbuf + xsl * 2048;
        bf16x8 A0 = *(const bf16x8*)(wb + (size_t)(hi * 256 + wm * 128 + 0 * 32 + ln31) * 8);
        bf16x8 A1 = *(const bf16x8*)(wb + (size_t)(hi * 256 + wm * 128 + 1 * 32 + ln31) * 8);
        bf16x8 A2 = *(const bf16x8*)(wb + (size_t)(hi * 256 + wm * 128 + 2 * 32 + ln31) * 8);
        bf16x8 A3 = *(const bf16x8*)(wb + (size_t)(hi * 256 + wm * 128 + 3 * 32 + ln31) * 8);
        bf16x8 Bf[2];
#pragma unroll
        for (int j = 0; j < 2; ++j)
            Bf[j] = *(const bf16x8*)(xb + (size_t)(hi * 128 + wn * 64 + j * 32 + ln31) * 8);
#pragma unroll
        for (int j = 0; j < 2; ++j) {
            acc[0][j]  = MFMA32(A0, Bf[j], acc[0][j]);
            acc[1][j]  = MFMA32(A1, Bf[j], acc[1][j]);
            acc2[0][j] = MFMA32(A2, Bf[j], acc2[0][j]);
            acc2[1][j] = MFMA32(A3, Bf[j], acc2[1][j]);
        }
    };

    // ---------------- layer 1: 48 k16-steps ----------------
    loadW(wrA, w1base, 0); loadXg(xrA, 0);
    loadW(wrB, w1base, 1); loadXg(xrB, 1);
    writeW(wrA, 0); writeX(xrA, 0);
    lgkm0_barrier();

    for (int c = 0; c < NS1 - 2; c += 2) {   // c = 0..44
        writeW(wrB, 1); writeX(xrB, 1);      // step c+1 (slot1 readers done at c-1)
        loadW(wrA, w1base, c + 2); loadXg(xrA, c + 2);
        comp(0, 0);                          // step c
        lgkm0_barrier();
        writeW(wrA, 0); writeX(xrA, 0);      // step c+2
        loadW(wrB, w1base, c + 3); loadXg(xrB, c + 3);   // c+3 <= 47
        comp(1, 1);                          // step c+1
        lgkm0_barrier();
    }
    // peel c=46: slot0=46, regs hold 47
    writeW(wrB, 1); writeX(xrB, 1);
    loadW(wrA, w2base, 0);                   // prefetch layer-2 steps 0,1 into regs
    loadW(wrB, w2base, 1);
    comp(0, 0);                              // step 46
    lgkm0_barrier();
    comp(1, 1);                              // step 47
    lgkm0_barrier();                         // all ds_reads retired before hbuf overwrite

    // W2 step0 -> wring slot0 (last slot0 readers: comp(46), pre-barrier)
    writeW(wrA, 0);

    // epilogue 1: bias + relu -> hbuf [blk=h/8][m=128][8h] (overwrites x ring region)
#pragma unroll
    for (int i = 0; i < 4; ++i) {
        const floatx16* a0 = (i < 2) ? &acc[i][0] : &acc2[i - 2][0];
#pragma unroll
        for (int g = 0; g < 4; ++g) {
            const int h0 = wm * 128 + i * 32 + g * 8 + 4 * hi;
            float4 bias = *(const float4*)(b1 + t * H_ + h0);
            const int blk = h0 >> 3;
#pragma unroll
            for (int j = 0; j < 2; ++j) {
                const int mm = wn * 64 + j * 32 + ln31;
                const floatx16& a = a0[j];
                bf16x4 o;
                o[0] = (bf16_t)fmaxf(a[4 * g + 0] + bias.x, 0.0f);
                o[1] = (bf16_t)fmaxf(a[4 * g + 1] + bias.y, 0.0f);
                o[2] = (bf16_t)fmaxf(a[4 * g + 2] + bias.z, 0.0f);
                o[3] = (bf16_t)fmaxf(a[4 * g + 3] + bias.w, 0.0f);
                *(bf16x4*)(hbuf + (size_t)(blk * BM_ + mm) * 8 + 4 * hi) = o;
            }
        }
    }
#pragma unroll
    for (int i = 0; i < 2; ++i)
#pragma unroll
        for (int j = 0; j < 2; ++j)
#pragma unroll
            for (int e = 0; e < 16; ++e) { acc[i][j][e] = 0.0f; acc2[i][j][e] = 0.0f; }

    lgkm0_barrier();                         // publishes h1 + W2 slot0

    // ---------------- layer 2: 16 k16-steps, B-frags from hbuf ----------------
    auto comp2 = [&](int c, int sl) {
        const bf16_t* wb = wring + sl * 4096;
        bf16x8 A0 = *(const bf16x8*)(wb + (size_t)(hi * 256 + wm * 128 + 0 * 32 + ln31) * 8);
        bf16x8 A1 = *(const bf16x8*)(wb + (size_t)(hi * 256 + wm * 128 + 1 * 32 + ln31) * 8);
        bf16x8 A2 = *(const bf16x8*)(wb + (size_t)(hi * 256 + wm * 128 + 2 * 32 + ln31) * 8);
        bf16x8 A3 = *(const bf16x8*)(wb + (size_t)(hi * 256 + wm * 128 + 3 * 32 + ln31) * 8);
        bf16x8 Bf[2];
        const int blk = c * 2 + hi;
#pragma unroll
        for (int j = 0; j < 2; ++j) {
            const int mm = wn * 64 + j * 32 + ln31;
            Bf[j] = *(const bf16x8*)(hbuf + (size_t)(blk * BM_ + mm) * 8);
        }
#pragma unroll
        for (int j = 0; j < 2; ++j) {
            acc[0][j]  = MFMA32(A0, Bf[j], acc[0][j]);
            acc[1][j]  = MFMA32(A1, Bf[j], acc[1][j]);
            acc2[0][j] = MFMA32(A2, Bf[j], acc2[0][j]);
            acc2[1][j] = MFMA32(A3, Bf[j], acc2[1][j]);
        }
    };

    for (int c = 0; c < NS2 - 2; c += 2) {   // c = 0..12
        writeW(wrB, 1);
        loadW(wrA, w2base, c + 2);
        comp2(c, 0);
        lgkm0_barrier();
        writeW(wrA, 0);
        loadW(wrB, w2base, c + 3);           // c+3 <= 15
        comp2(c + 1, 1);
        lgkm0_barrier();
    }
    // peel c=14: slot0=14, wrB=15
    writeW(wrB, 1);
    comp2(14, 0);
    lgkm0_barrier();
    w3s[tid] = W3[t * H_ + tid];             // slot0 free (256 threads == 256 floats)
    comp2(15, 1);
    lgkm0_barrier();                         // w3s visible; hbuf reads done

    // epilogue 2: bias + relu -> h2 in hbuf (same layout)
#pragma unroll
    for (int i = 0; i < 4; ++i) {
        const floatx16* a0 = (i < 2) ? &acc[i][0] : &acc2[i - 2][0];
#pragma unroll
        for (int g = 0; g < 4; ++g) {
            const int h0 = wm * 128 + i * 32 + g * 8 + 4 * hi;
            float4 bias = *(const float4*)(b2 + t * H_ + h0);
            const int blk = h0 >> 3;
#pragma unroll
            for (int j = 0; j < 2; ++j) {
                const int mm = wn * 64 + j * 32 + ln31;
                const floatx16& a = a0[j];
                bf16x4 o;
                o[0] = (bf16_t)fmaxf(a[4 * g + 0] + bias.x, 0.0f);
                o[1] = (bf16_t)fmaxf(a[4 * g + 1] + bias.y, 0.0f);
                o[2] = (bf16_t)fmaxf(a[4 * g + 2] + bias.z, 0.0f);
                o[3] = (bf16_t)fmaxf(a[4 * g + 3] + bias.w, 0.0f);
                *(bf16x4*)(hbuf + (size_t)(blk * BM_ + mm) * 8 + 4 * hi) = o;
            }
        }
    }
    lgkm0_barrier();

    // ---------------- layer 3: out[m,t] = h2[m,:]·W3 + b3[t] ----------------
    {
        const int m = tid >> 1, seg = tid & 1;   // 2 threads/row, 128 h each
        float sum = 0.0f;
#pragma unroll
        for (int b = 0; b < 16; ++b) {
            const int blk = seg * 16 + b;
            const bf16x8 v = *(const bf16x8*)(hbuf + (size_t)(blk * BM_ + m) * 8);
            const float* w = w3s + blk * 8;
#pragma unroll
            for (int e = 0; e < 8; ++e) sum += (float)v[e] * w[e];
        }
        sum += __shfl_xor(sum, 1);
        if (seg == 0) out[(size_t)(m0 + m) * T_ + t] = sum + b3[t];
    }
}

extern "C" void kernel_launch(void* const* d_in, const int* in_sizes, int n_in,
                              void* d_out, int out_size, void* d_ws, size_t ws_size,
                              hipStream_t stream) {
    const float* x  = (const float*)d_in[0];
    const float* W1 = (const float*)d_in[1];
    const float* b1 = (const float*)d_in[2];
    const float* W2 = (const float*)d_in[3];
    const float* b2 = (const float*)d_in[4];
    const float* W3 = (const float*)d_in[5];
    const float* b3 = (const float*)d_in[6];
    float* out = (float*)d_out;

    const size_t nx  = (size_t)B_ * IN_;
    const size_t nw1 = (size_t)T_ * IN_ * H_;

    bf16_t* xt  = (bf16_t*)d_ws;
    bf16_t* w1t = xt + nx;
    bf16_t* w2t = w1t + nw1;

    tile_all<<<dim3(T_ * KC1 + T_ * 8 + 32 * KC1), 256, 0, stream>>>(x, W1, W2, xt, w1t, w2t);
    mtmlp_fused7<<<dim3(4096), 256, 0, stream>>>(xt, w1t, b1, w2t, b2, W3, b3, out);
}